// Round 4
// baseline (76.507 us; speedup 1.0000x reference)
//
#include <hip/hip_runtime.h>
#include <hip/hip_bf16.h>

// Problem constants (from reference): N=128 nodes, H=2 heads, L=1024.
#define NN 128
#define HH 2
#define LL 1024
#define NH (NN * HH)          // 256 rows
#define NHL (NN * HH * LL)    // 262144 elements per (n,h,l) tensor
#define COLS (HH * LL)        // 2048 columns of the alpha matrix

// Fused single-dispatch kernel. 256 blocks x 256 threads (trivial VGPR/LDS
// use -> all blocks co-resident on 256 CUs).
//
// Phase 1: block b = row scan of (n,h) row b — relu, cumsum (-> Ss), linear
//   decay recurrence Is[i] = d*Is[i-1] + s[i] (-> alpha). Wave shuffle scans
//   + one LDS exchange of 4 wave totals. Chunk ratio D = d^4, wave ratio
//   W = D^64.
// Barrier: agent-scope release fetch_add on a counter living in d_ws. The
//   harness poisons d_ws to 0xAA bytes before every launch, so the counter
//   deterministically starts at 0xAAAAAAAA; target = base + 256. Bounded
//   spin so a broken poison assumption fails validation instead of hanging.
// Phase 2: block b = k-tiled mix for rowgroup (b>>3), colgroup (b&7):
//   Alpha[k,col] = alpha[k,col] + sum_m Amat[k,m]*alpha[m,col];
//   pred = Alpha * Ss. Plus tmatT = Amat + I from the first 16 blocks.
__global__ __launch_bounds__(256) void fused_kernel(
    const float* __restrict__ x, const float* __restrict__ Amat,
    const float* __restrict__ taus, const float* __restrict__ r0d,
    float* __restrict__ out_pred, float* __restrict__ out_signal,
    float* __restrict__ out_tmatT, float* __restrict__ ws_alpha,
    float* __restrict__ ws_ss, unsigned int* __restrict__ barrier_ctr) {
  const int bid = blockIdx.x;   // 0..255
  const int tid = threadIdx.x;  // 0..255
  const int lane = tid & 63;
  const int wave = tid >> 6;

  // ---------------- Phase 1: scan row `bid` ----------------
  const int row = bid;  // n*H + h
  const float4* xr = (const float4*)(x + (size_t)row * LL);
  float4 v = xr[tid];
  float s0 = fmaxf(v.x, 0.f);
  float s1 = fmaxf(v.y, 0.f);
  float s2 = fmaxf(v.z, 0.f);
  float s3 = fmaxf(v.w, 0.f);

  const float tau = taus[row];
  const float d = 1.f - 1.f / tau;  // == exp(log(1 - 1/tau))
  const float R0 = r0d[row];

  // thread-local inclusive prefix sums (chunk of 4)
  float c0 = s0, c1 = c0 + s1, c2 = c1 + s2, c3 = c2 + s3;
  // thread-local decay recurrence (zero incoming state)
  float l0 = s0;
  float l1 = fmaf(d, l0, s1);
  float l2 = fmaf(d, l1, s2);
  float l3 = fmaf(d, l2, s3);

  // in-wave weighted inclusive scan over (chunk sum, chunk-end state)
  float vs = c3;
  float vi = l3;
  float D = d * d;
  D = D * D;     // d^4
  float Dp = D;  // D^off
#pragma unroll
  for (int off = 1; off < 64; off <<= 1) {
    float ps = __shfl_up(vs, off);
    float pi = __shfl_up(vi, off);
    if (lane >= off) {
      vs += ps;
      vi = fmaf(Dp, pi, vi);
    }
    Dp *= Dp;
  }
  // Dp == D^64 == wave ratio W

  __shared__ float tw_s[4];
  __shared__ float tw_i[4];
  if (lane == 63) {
    tw_s[wave] = vs;
    tw_i[wave] = vi;
  }
  __syncthreads();

  // wave-incoming totals (sequential combine over earlier waves)
  float S_in = 0.f, I_in = 0.f;
  for (int u = 0; u < wave; ++u) {
    S_in += tw_s[u];
    I_in = fmaf(I_in, Dp, tw_i[u]);  // I = I*W + I_u
  }

  // per-lane exclusive (state at end of previous chunk, within wave)
  float es = __shfl_up(vs, 1);
  float ei = __shfl_up(vi, 1);
  if (lane == 0) {
    es = 0.f;
    ei = 0.f;
  }
  const float exs = S_in + es;
  // wave-incoming state decays D^lane before reaching this chunk (D>0)
  const float state = fmaf(I_in, exp2f((float)lane * log2f(D)), ei);

  // finalize per element
  float cum0 = exs + c0, cum1 = exs + c1, cum2 = exs + c2, cum3 = exs + c3;
  float is0 = fmaf(d, state, s0);
  float is1 = fmaf(d, is0, s1);
  float is2 = fmaf(d, is1, s2);
  float is3 = fmaf(d, is2, s3);

  float4 sig = make_float4(s0, s1, s2, s3);
  float4 ss = make_float4(1.f - cum0, 1.f - cum1, 1.f - cum2, 1.f - cum3);
  float4 al = make_float4(1.f - __expf(-R0 * is0), 1.f - __expf(-R0 * is1),
                          1.f - __expf(-R0 * is2), 1.f - __expf(-R0 * is3));

  const size_t base = (size_t)row * LL / 4 + tid;
  ((float4*)(out_signal))[base] = sig;  // output 1: signal
  ((float4*)(ws_alpha))[base] = al;
  ((float4*)(ws_ss))[base] = ss;

  // tmatT = Amat + I (16384 elements; first 16 blocks, float4 per thread).
  // Emitted here (phase 1) — independent of the barrier.
  const int fid = bid * 256 + tid;
  if (fid < NN * NN / 4) {
    float4 t = ((const float4*)Amat)[fid];
    const int e = fid << 2;
    if (((e + 0) % (NN + 1)) == 0) t.x += 1.f;
    if (((e + 1) % (NN + 1)) == 0) t.y += 1.f;
    if (((e + 2) % (NN + 1)) == 0) t.z += 1.f;
    if (((e + 3) % (NN + 1)) == 0) t.w += 1.f;
    ((float4*)out_tmatT)[fid] = t;
  }

  // ---------------- Device-scope arrival barrier ----------------
  // Counter starts at the harness poison value 0xAAAAAAAA (0xAA bytes).
  const unsigned int kTarget = 0xAAAAAAAAu + (unsigned int)NH;
  __syncthreads();  // all phase-1 stores of this block issued
  if (tid == 0) {
    // release: publish this block's ws_alpha/ws_ss device-wide
    __hip_atomic_fetch_add(barrier_ctr, 1u, __ATOMIC_RELEASE,
                           __HIP_MEMORY_SCOPE_AGENT);
    // acquire-spin until all 256 blocks have arrived (bounded: no hang)
    unsigned int spins = 0;
    while (__hip_atomic_load(barrier_ctr, __ATOMIC_ACQUIRE,
                             __HIP_MEMORY_SCOPE_AGENT) != kTarget &&
           spins < (1u << 20)) {
      ++spins;
      __builtin_amdgcn_s_sleep(1);
    }
  }
  __syncthreads();  // fan the acquire out to the whole block

  // ---------------- Phase 2: mix for (rowgroup, colgroup) ----------------
  const int rg = bid >> 3;                                 // 32 rowgroups
  const int cg = bid & 7;                                  // 8 colgroups
  const int col = (cg << 8) + tid;                         // 0..2047
  const int k0 = __builtin_amdgcn_readfirstlane(rg << 2);  // block-uniform

  const float* __restrict__ a0 = Amat + (k0 + 0) * NN;
  const float* __restrict__ a1 = Amat + (k0 + 1) * NN;
  const float* __restrict__ a2 = Amat + (k0 + 2) * NN;
  const float* __restrict__ a3 = Amat + (k0 + 3) * NN;

  // +I term
  float acc0 = ws_alpha[(size_t)(k0 + 0) * COLS + col];
  float acc1 = ws_alpha[(size_t)(k0 + 1) * COLS + col];
  float acc2 = ws_alpha[(size_t)(k0 + 2) * COLS + col];
  float acc3 = ws_alpha[(size_t)(k0 + 3) * COLS + col];

  const float* __restrict__ ac = ws_alpha + col;
#pragma unroll 8
  for (int m = 0; m < NN; ++m) {
    const float av = ac[(size_t)m * COLS];
    acc0 = fmaf(a0[m], av, acc0);
    acc1 = fmaf(a1[m], av, acc1);
    acc2 = fmaf(a2[m], av, acc2);
    acc3 = fmaf(a3[m], av, acc3);
  }

  out_pred[(size_t)(k0 + 0) * COLS + col] =
      acc0 * ws_ss[(size_t)(k0 + 0) * COLS + col];
  out_pred[(size_t)(k0 + 1) * COLS + col] =
      acc1 * ws_ss[(size_t)(k0 + 1) * COLS + col];
  out_pred[(size_t)(k0 + 2) * COLS + col] =
      acc2 * ws_ss[(size_t)(k0 + 2) * COLS + col];
  out_pred[(size_t)(k0 + 3) * COLS + col] =
      acc3 * ws_ss[(size_t)(k0 + 3) * COLS + col];
}

extern "C" void kernel_launch(void* const* d_in, const int* in_sizes, int n_in,
                              void* d_out, int out_size, void* d_ws,
                              size_t ws_size, hipStream_t stream) {
  const float* x = (const float*)d_in[0];     // (128,2,1024)
  const float* Amat = (const float*)d_in[1];  // (128,128)
  const float* taus = (const float*)d_in[2];  // (128,2)
  const float* r0d = (const float*)d_in[3];   // (128,2)

  float* out = (float*)d_out;
  float* out_pred = out;             // (128,2,1024)
  float* out_signal = out + NHL;     // (128,2,1024)
  float* out_tmatT = out + 2 * NHL;  // (128,128) = Amat + I

  float* ws = (float*)d_ws;
  float* ws_alpha = ws;                                  // NHL floats
  float* ws_ss = ws + NHL;                               // NHL floats
  unsigned int* barrier_ctr = (unsigned int*)(ws + 2 * NHL);  // 1 uint

  fused_kernel<<<NH, 256, 0, stream>>>(x, Amat, taus, r0d, out_pred,
                                       out_signal, out_tmatT, ws_alpha, ws_ss,
                                       barrier_ctr);
}

// Round 5
// 69.770 us; speedup vs baseline: 1.0966x; 1.0966x over previous
//
#include <hip/hip_runtime.h>
#include <hip/hip_bf16.h>

// Problem constants (from reference): N=128 nodes, H=2 heads, L=1024.
#define NN 128
#define HH 2
#define LL 1024
#define NH (NN * HH)          // 256 rows
#define NHL (NN * HH * LL)    // 262144 elements per (n,h,l) tensor
#define COLS (HH * LL)        // 2048 columns of the alpha matrix

// NOTE (R4 post-mortem): fusing these two kernels with an agent-scope
// arrival barrier REGRESSED +7.6 us — the release/acquire pair forces
// per-block L2 writeback/invalidate (per-XCD L2s are non-coherent), which
// both serializes and evicts the alpha tile phase 2 streams from L2. The
// kernel boundary's single runtime-managed flush is cheaper. Keep 2 kernels.

// Kernel 1: per-(n,h) row — relu, cumsum (-> Ss), linear decay recurrence
// (-> Is -> alpha). One block of 256 threads per row; each thread owns 4
// consecutive elements. Wave-level shuffle scans (no barrier) + one LDS
// exchange of the 4 wave totals (1 barrier). Recurrence Is[i]=d*Is[i-1]+s[i]
// with uniform per-row ratio: chunk ratio D = d^4, wave ratio W = D^64.
// Blocks 0..15 also emit tmatT = Amat + I (input-only, independent).
__global__ __launch_bounds__(256) void row_scan_kernel(
    const float* __restrict__ x, const float* __restrict__ taus,
    const float* __restrict__ r0d, const float* __restrict__ Amat,
    float* __restrict__ out_signal, float* __restrict__ out_tmatT,
    float* __restrict__ ws_alpha, float* __restrict__ ws_ss) {
  const int row = blockIdx.x;   // n*H + h
  const int tid = threadIdx.x;  // 0..255
  const int lane = tid & 63;
  const int wave = tid >> 6;

  const float4* xr = (const float4*)(x + (size_t)row * LL);
  float4 v = xr[tid];
  float s0 = fmaxf(v.x, 0.f);
  float s1 = fmaxf(v.y, 0.f);
  float s2 = fmaxf(v.z, 0.f);
  float s3 = fmaxf(v.w, 0.f);

  const float tau = taus[row];
  const float d = 1.f - 1.f / tau;  // == exp(log(1 - 1/tau))
  const float R0 = r0d[row];

  // thread-local inclusive prefix sums (chunk of 4)
  float c0 = s0, c1 = c0 + s1, c2 = c1 + s2, c3 = c2 + s3;
  // thread-local decay recurrence (zero incoming state)
  float l0 = s0;
  float l1 = fmaf(d, l0, s1);
  float l2 = fmaf(d, l1, s2);
  float l3 = fmaf(d, l2, s3);

  // in-wave weighted inclusive scan over (chunk sum, chunk-end state)
  float vs = c3;
  float vi = l3;
  float D = d * d;
  D = D * D;     // d^4
  float Dp = D;  // D^off
#pragma unroll
  for (int off = 1; off < 64; off <<= 1) {
    float ps = __shfl_up(vs, off);
    float pi = __shfl_up(vi, off);
    if (lane >= off) {
      vs += ps;
      vi = fmaf(Dp, pi, vi);
    }
    Dp *= Dp;
  }
  // Dp == D^64 == wave ratio W

  __shared__ float tw_s[4];
  __shared__ float tw_i[4];
  if (lane == 63) {
    tw_s[wave] = vs;
    tw_i[wave] = vi;
  }
  __syncthreads();

  // wave-incoming totals (sequential combine over earlier waves)
  float S_in = 0.f, I_in = 0.f;
  for (int u = 0; u < wave; ++u) {
    S_in += tw_s[u];
    I_in = fmaf(I_in, Dp, tw_i[u]);  // I = I*W + I_u
  }

  // per-lane exclusive (state at end of previous chunk, within wave)
  float es = __shfl_up(vs, 1);
  float ei = __shfl_up(vi, 1);
  if (lane == 0) {
    es = 0.f;
    ei = 0.f;
  }
  const float exs = S_in + es;
  // wave-incoming state decays D^lane before reaching this chunk (D>0)
  const float state = fmaf(I_in, exp2f((float)lane * log2f(D)), ei);

  // finalize per element
  float cum0 = exs + c0, cum1 = exs + c1, cum2 = exs + c2, cum3 = exs + c3;
  float is0 = fmaf(d, state, s0);
  float is1 = fmaf(d, is0, s1);
  float is2 = fmaf(d, is1, s2);
  float is3 = fmaf(d, is2, s3);

  float4 sig = make_float4(s0, s1, s2, s3);
  float4 ss = make_float4(1.f - cum0, 1.f - cum1, 1.f - cum2, 1.f - cum3);
  float4 al = make_float4(1.f - __expf(-R0 * is0), 1.f - __expf(-R0 * is1),
                          1.f - __expf(-R0 * is2), 1.f - __expf(-R0 * is3));

  const size_t base = (size_t)row * LL / 4 + tid;
  ((float4*)(out_signal))[base] = sig;  // output 1: signal
  ((float4*)(ws_alpha))[base] = al;
  ((float4*)(ws_ss))[base] = ss;

  // tmatT = Amat + I (16384 elements; blocks 0..15, float4 per thread)
  const int fid = row * 256 + tid;
  if (fid < NN * NN / 4) {
    float4 t = ((const float4*)Amat)[fid];
    const int e = fid << 2;
    if (((e + 0) % (NN + 1)) == 0) t.x += 1.f;
    if (((e + 1) % (NN + 1)) == 0) t.y += 1.f;
    if (((e + 2) % (NN + 1)) == 0) t.z += 1.f;
    if (((e + 3) % (NN + 1)) == 0) t.w += 1.f;
    ((float4*)out_tmatT)[fid] = t;
  }
}

// Kernel 2: Alpha[k,col] = alpha[k,col] + sum_m Amat[k,m]*alpha[m,col];
// predSignal = Alpha * Ss. k-tiled by 4: each thread computes one column for
// 4 consecutive k rows — each alpha[m,col] load feeds 4 FMAs (32 MB L2-side
// read traffic, 128 KB/CU). 256 blocks (32 rowgroups x 8 colgroups) keep the
// traffic spread across all CUs. A-row weights are block-uniform -> scalar
// pipe via readfirstlane.
__global__ __launch_bounds__(256) void mix_kernel(
    const float* __restrict__ Amat, const float* __restrict__ ws_alpha,
    const float* __restrict__ ws_ss, float* __restrict__ pred) {
  const int bid = blockIdx.x;  // 0..255
  const int tid = threadIdx.x;
  const int rg = bid >> 3;                                 // 32 rowgroups
  const int cg = bid & 7;                                  // 8 colgroups
  const int col = (cg << 8) + tid;                         // 0..2047
  const int k0 = __builtin_amdgcn_readfirstlane(rg << 2);  // block-uniform

  const float* __restrict__ a0 = Amat + (k0 + 0) * NN;
  const float* __restrict__ a1 = Amat + (k0 + 1) * NN;
  const float* __restrict__ a2 = Amat + (k0 + 2) * NN;
  const float* __restrict__ a3 = Amat + (k0 + 3) * NN;

  // +I term
  float acc0 = ws_alpha[(size_t)(k0 + 0) * COLS + col];
  float acc1 = ws_alpha[(size_t)(k0 + 1) * COLS + col];
  float acc2 = ws_alpha[(size_t)(k0 + 2) * COLS + col];
  float acc3 = ws_alpha[(size_t)(k0 + 3) * COLS + col];

  const float* __restrict__ ac = ws_alpha + col;
#pragma unroll 8
  for (int m = 0; m < NN; ++m) {
    const float av = ac[(size_t)m * COLS];
    acc0 = fmaf(a0[m], av, acc0);
    acc1 = fmaf(a1[m], av, acc1);
    acc2 = fmaf(a2[m], av, acc2);
    acc3 = fmaf(a3[m], av, acc3);
  }

  pred[(size_t)(k0 + 0) * COLS + col] =
      acc0 * ws_ss[(size_t)(k0 + 0) * COLS + col];
  pred[(size_t)(k0 + 1) * COLS + col] =
      acc1 * ws_ss[(size_t)(k0 + 1) * COLS + col];
  pred[(size_t)(k0 + 2) * COLS + col] =
      acc2 * ws_ss[(size_t)(k0 + 2) * COLS + col];
  pred[(size_t)(k0 + 3) * COLS + col] =
      acc3 * ws_ss[(size_t)(k0 + 3) * COLS + col];
}

extern "C" void kernel_launch(void* const* d_in, const int* in_sizes, int n_in,
                              void* d_out, int out_size, void* d_ws,
                              size_t ws_size, hipStream_t stream) {
  const float* x = (const float*)d_in[0];     // (128,2,1024)
  const float* Amat = (const float*)d_in[1];  // (128,128)
  const float* taus = (const float*)d_in[2];  // (128,2)
  const float* r0d = (const float*)d_in[3];   // (128,2)

  float* out = (float*)d_out;
  float* out_pred = out;             // (128,2,1024)
  float* out_signal = out + NHL;     // (128,2,1024)
  float* out_tmatT = out + 2 * NHL;  // (128,128) = Amat + I

  float* ws = (float*)d_ws;
  float* ws_alpha = ws;     // NHL floats
  float* ws_ss = ws + NHL;  // NHL floats

  row_scan_kernel<<<NH, 256, 0, stream>>>(x, taus, r0d, Amat, out_signal,
                                          out_tmatT, ws_alpha, ws_ss);
  mix_kernel<<<256, 256, 0, stream>>>(Amat, ws_alpha, ws_ss, out_pred);
}